// Round 10
// baseline (558.865 us; speedup 1.0000x reference)
//
#include <hip/hip_runtime.h>
#include <math.h>

#define N_NODES 50000
#define M_ENS   20
#define C_IN    32
#define H       128
#define E_EDGES 800000
#define L_LAYERS 3
#define BN_EPS  1e-5f

typedef unsigned short u16;
typedef unsigned int   u32;

typedef __attribute__((ext_vector_type(8))) short bf16x8;  // 8 bf16 = 4 VGPR
typedef __attribute__((ext_vector_type(4))) float f32x4;

#define MFMA16(a, b, c) __builtin_amdgcn_mfma_f32_16x16x32_bf16((a), (b), (c), 0, 0, 0)

// bf16 helpers (RNE pack, cheap unpack)
__device__ __forceinline__ float bf_lo(u32 p) {
    union { u32 u; float f; } v; v.u = p << 16; return v.f;
}
__device__ __forceinline__ float bf_hi(u32 p) {
    union { u32 u; float f; } v; v.u = p & 0xFFFF0000u; return v.f;
}
__device__ __forceinline__ u16 f2bf(float f) {
    union { float f; u32 u; } v; v.f = f;
    const u32 r = v.u + 0x7FFFu + ((v.u >> 16) & 1u);
    return (u16)(r >> 16);
}
__device__ __forceinline__ float bfu(u16 h) {
    union { u32 u; float f; } v; v.u = (u32)h << 16; return v.f;
}
__device__ __forceinline__ u32 pack2bf(float a, float b) {
    return (u32)f2bf(a) | ((u32)f2bf(b) << 16);
}

// split f32[8] -> (hi, lo) bf16x8 fragments
__device__ __forceinline__ void split8(const float* a, bf16x8& h, bf16x8& l) {
    #pragma unroll
    for (int j = 0; j < 8; ++j) {
        const u16 hv = f2bf(a[j]);
        h[j] = (short)hv;
        l[j] = (short)f2bf(a[j] - bfu(hv));
    }
}

// ---------------------------------------------------------------------------
// k_fold: precompute folded weights (unchanged).
// ---------------------------------------------------------------------------
__global__ __launch_bounds__(256) void k_fold(
    const float* __restrict__ w2,  const float* __restrict__ b2,
    const float* __restrict__ rw1, const float* __restrict__ rb1,
    const float* __restrict__ rw2, const float* __restrict__ rb2,
    const float* __restrict__ dr_w, const float* __restrict__ dr_b,
    float* __restrict__ Wf1, float* __restrict__ bf1,
    float* __restrict__ Wf2, float* __restrict__ bf2)
{
    const int g = blockIdx.x >> 7;
    const int j = blockIdx.x & 127;
    const int t = threadIdx.x;

    const float* A  = g ? rw2 : w2;
    const float* Bm = g ? (dr_w + C_IN * H) : rw1;

    __shared__ float s_col[H];
    if (t < H) s_col[t] = Bm[t * H + j];
    __syncthreads();

    const int r = t >> 1, q = t & 1;
    const float* arow = &A[r * H + q * 64];
    const float* cp = &s_col[q * 64];
    float acc = 0.f;
    #pragma unroll
    for (int u = 0; u < 64; u += 4) {
        const float4 av = *(const float4*)&arow[u];
        acc = fmaf(av.x, cp[u], acc);
        acc = fmaf(av.y, cp[u + 1], acc);
        acc = fmaf(av.z, cp[u + 2], acc);
        acc = fmaf(av.w, cp[u + 3], acc);
    }
    acc += __shfl_xor(acc, 1);
    if (q == 0) (g ? Wf2 : Wf1)[r * H + j] = acc;

    if (t == 0) {
        float bacc = g ? dr_b[j] : rb1[j];
        const float* bsrc = g ? rb2 : b2;
        const float scale = g ? 1.f : 20.f;
        for (int k = 0; k < H; ++k)
            bacc = fmaf(scale * bsrc[k], s_col[k], bacc);
        (g ? bf2 : bf1)[j] = bacc;
    }
}

// ---------------------------------------------------------------------------
// k_pack: repack mlp_w1/mlp_w2 into MFMA B-fragment order, split-bf16 (hi/lo).
// ---------------------------------------------------------------------------
__global__ __launch_bounds__(256) void k_pack(
    const float* __restrict__ w1, const float* __restrict__ w2,
    u16* __restrict__ wpk)
{
    const int tid = blockIdx.x * 256 + threadIdx.x;   // 3*2*4*8*64*8 = 98304
    const int j    = tid & 7;
    const int lane = (tid >> 3) & 63;
    const int nt   = (tid >> 9) & 7;
    const int ks   = (tid >> 12) & 3;
    const int mat  = (tid >> 14) & 1;
    const int l    = tid >> 15;
    if (l >= L_LAYERS) return;

    const int k = ks * 32 + (lane >> 4) * 8 + j;
    const int n = nt * 16 + (lane & 15);
    const float* w = (mat ? w2 : w1) + (size_t)l * H * H;
    const float v = w[k * H + n];

    const u16 hi = f2bf(v);
    const float lo = v - bfu(hi);

    u16* base = wpk + ((size_t)(l * 2 + mat)) * 32768;   // 2 parts * 16384
    const int idx = (ks * 8 + nt) * 512 + lane * 8 + j;
    base[idx] = hi;
    base[16384 + idx] = f2bf(lo);
}

// ---------------------------------------------------------------------------
// k_pack2: pack embed-path weights into MFMA B-fragment order, split hi/lo.
// ---------------------------------------------------------------------------
#define PW1H 0
#define PW1L 4096
#define WF1H 8192
#define WF1L 24576
#define WF2H 40960
#define WF2L 57344
#define DRH  73728
#define DRL  77824
__global__ __launch_bounds__(256) void k_pack2(
    const float* __restrict__ phi_w1, const float* __restrict__ Wf1,
    const float* __restrict__ Wf2,    const float* __restrict__ dr_w,
    u16* __restrict__ pk)
{
    const int tid = blockIdx.x * 256 + threadIdx.x;   // 40960 total
    int idx; const float* src; int bh; int bl;
    if (tid < 4096)       { idx = tid;         src = phi_w1; bh = PW1H; bl = PW1L; }
    else if (tid < 20480) { idx = tid - 4096;  src = Wf1;    bh = WF1H; bl = WF1L; }
    else if (tid < 36864) { idx = tid - 20480; src = Wf2;    bh = WF2H; bl = WF2L; }
    else if (tid < 40960) { idx = tid - 36864; src = dr_w;   bh = DRH;  bl = DRL;  }
    else return;

    const int j    = idx & 7;
    const int lane = (idx >> 3) & 63;
    const int nt   = (idx >> 9) & 7;
    const int ks   = idx >> 12;
    const int k = ks * 32 + (lane >> 4) * 8 + j;
    const int n = nt * 16 + (lane & 15);
    const float v = src[k * H + n];
    const u16 hi = f2bf(v);
    pk[bh + idx] = hi;
    pk[bl + idx] = f2bf(v - bfu(hi));
}

// ---------------------------------------------------------------------------
// k_embed v5: FUSED phi + matmul chain (R3's split, un-split).
// The split's purpose (fix latency-bound monolith) was superseded by R6-R9:
// the real cost was uncoalesced staging, now fixed. Fusing removes the
// 25.6 MB hh/hl write + 25.6 MB re-read round-trip, a kernel launch, and
// k_emb2's re-stage. One 40 KB LDS region is time-shared:
//   [stage ensemble swizzled] B1 [phi MFMA reads] B2 [phi split tiles
//   s_hh/s_hl, 16x136] B3 [mm1 -> s_th/s_tl] B4 [mm2+x@dr -> s_ho] B5
//   [coalesced h_out copy]
// All math identical to R9's k_phi v4 + k_emb2 v2 -> bit-identical h.
// ---------------------------------------------------------------------------
__global__ __launch_bounds__(256) void k_embed(
    const float* __restrict__ ensemble, const float* __restrict__ x,
    const float* __restrict__ phi_b1,
    const float* __restrict__ bf1, const float* __restrict__ bf2,
    const u16* __restrict__ pk,
    u16* __restrict__ h_out)
{
    const int n0 = blockIdx.x * 16;
    const int t  = threadIdx.x;
    const int lane = t & 63;
    const int w    = t >> 6;
    const int l15  = lane & 15;
    const int kl   = lane >> 4;
    const int nt0  = w * 2, nt1 = nt0 + 1;
    const int nA   = nt0 * 16 + l15, nB = nt1 * 16 + l15;

    __shared__ __align__(16) char s_mem[16 * M_ENS * C_IN * 4];   // 40960 B
    u16* s_hh = (u16*)s_mem;                 // 16*136 u16 = 4352 B
    u16* s_hl = (u16*)(s_mem + 4352);
    u16* s_th = (u16*)(s_mem + 8704);
    u16* s_tl = (u16*)(s_mem + 13056);
    u16* s_ho = (u16*)s_mem;                 // reuse (s_hh dead after mm1)

    // ---- stage: linear coalesced ensemble loads into registers ----
    const char* gsrc = (const char*)(ensemble + (size_t)n0 * (M_ENS * C_IN));
    float4 st[10];
    #pragma unroll
    for (int it = 0; it < 10; ++it)
        st[it] = *(const float4*)(gsrc + it * 4096 + w * 1024 + lane * 16);

    // x loads for mm2, issued early
    const float* xb = x + (size_t)(n0 + l15) * C_IN + kl * 8;
    const float4 xv0 = *(const float4*)xb;
    const float4 xv1 = *(const float4*)(xb + 4);

    // phi B fragments + bias while loads are in flight
    bf16x8 pbh[8], pbl[8];
    #pragma unroll
    for (int nt = 0; nt < 8; ++nt) {
        pbh[nt] = *(const bf16x8*)&pk[PW1H + nt * 512 + lane * 8];
        pbl[nt] = *(const bf16x8*)&pk[PW1L + nt * 512 + lane * 8];
    }
    float b1v[8];
    #pragma unroll
    for (int nt = 0; nt < 8; ++nt) b1v[nt] = phi_b1[nt * 16 + l15];

    // ---- swizzled LDS writes of the ensemble chunk ----
    #pragma unroll
    for (int it = 0; it < 10; ++it) {
        const int o   = it * 4096 + w * 1024 + lane * 16;
        const int row = o >> 7;
        *(float4*)(s_mem + (o ^ ((row & 7) << 4))) = st[it];
    }
    __syncthreads();                                     // B1

    // ---- phi MFMA: acc[r][nt] over 5 M-tiles ----
    float acc[4][8];
    #pragma unroll
    for (int r = 0; r < 4; ++r)
        #pragma unroll
        for (int nt = 0; nt < 8; ++nt) acc[r][nt] = 0.f;

    #pragma unroll
    for (int tt = 0; tt < 5; ++tt) {
        const int node = w * 4 + (l15 & 3);
        const int row  = node * M_ENS + (l15 >> 2) * 5 + tt;
        const int a0   = row * 128 + kl * 32;
        const int s0   = a0 ^ ((row & 7) << 4);
        const float4 v0 = *(const float4*)(s_mem + s0);
        const float4 v1 = *(const float4*)(s_mem + (s0 ^ 16));
        float a8[8] = {v0.x, v0.y, v0.z, v0.w, v1.x, v1.y, v1.z, v1.w};
        bf16x8 ah, al;
        split8(a8, ah, al);
        #pragma unroll
        for (int nt = 0; nt < 8; ++nt) {
            f32x4 c = {0.f, 0.f, 0.f, 0.f};
            c = MFMA16(ah, pbh[nt], c);
            c = MFMA16(al, pbh[nt], c);
            c = MFMA16(ah, pbl[nt], c);
            #pragma unroll
            for (int r = 0; r < 4; ++r)
                acc[r][nt] += fmaxf(c[r] + b1v[nt], 0.f);
        }
    }

    // m-sum across the 4 kl groups (each holds 5 of the 20 members)
    #pragma unroll
    for (int r = 0; r < 4; ++r)
        #pragma unroll
        for (int nt = 0; nt < 8; ++nt) {
            float v = acc[r][nt];
            v += __shfl_xor(v, 16);
            v += __shfl_xor(v, 32);
            acc[r][nt] = v;
        }
    __syncthreads();                                     // B2 (s_ens dead)

    // ---- phi split tiles into LDS (16x136, conflict-free frag layout) ----
    #pragma unroll
    for (int r = 0; r < 4; ++r) {
        if (kl == r) {
            const int node = w * 4 + r;
            #pragma unroll
            for (int nt = 0; nt < 8; ++nt) {
                const float v = acc[r][nt];
                const u16 hv = f2bf(v);
                s_hh[node * 136 + nt * 16 + l15] = hv;
                s_hl[node * 136 + nt * 16 + l15] = f2bf(v - bfu(hv));
            }
        }
    }
    __syncthreads();                                     // B3

    // ---- mm1: t = relu(hsum @ Wf1 + bf1) ----
    {
        f32x4 acc0 = {0.f, 0.f, 0.f, 0.f};
        f32x4 acc1 = {0.f, 0.f, 0.f, 0.f};
        #pragma unroll
        for (int ks = 0; ks < 4; ++ks) {
            const int aoff = l15 * 136 + ks * 32 + kl * 8;
            const bf16x8 ah = *(const bf16x8*)&s_hh[aoff];
            const bf16x8 al = *(const bf16x8*)&s_hl[aoff];
            const int bo0 = (ks * 8 + nt0) * 512 + lane * 8;
            const int bo1 = (ks * 8 + nt1) * 512 + lane * 8;
            const bf16x8 bh0 = *(const bf16x8*)&pk[WF1H + bo0];
            const bf16x8 bl0 = *(const bf16x8*)&pk[WF1L + bo0];
            const bf16x8 bh1 = *(const bf16x8*)&pk[WF1H + bo1];
            const bf16x8 bl1 = *(const bf16x8*)&pk[WF1L + bo1];
            acc0 = MFMA16(ah, bh0, acc0);
            acc0 = MFMA16(al, bh0, acc0);
            acc0 = MFMA16(ah, bl0, acc0);
            acc1 = MFMA16(ah, bh1, acc1);
            acc1 = MFMA16(al, bh1, acc1);
            acc1 = MFMA16(ah, bl1, acc1);
        }
        const float bA = bf1[nA], bB = bf1[nB];
        #pragma unroll
        for (int r = 0; r < 4; ++r) {
            const int m = kl * 4 + r;
            const float t0 = fmaxf(acc0[r] + bA, 0.f);
            const float t1 = fmaxf(acc1[r] + bB, 0.f);
            const u16 h0 = f2bf(t0), h1 = f2bf(t1);
            s_th[m * 136 + nA] = h0;
            s_tl[m * 136 + nA] = f2bf(t0 - bfu(h0));
            s_th[m * 136 + nB] = h1;
            s_tl[m * 136 + nB] = f2bf(t1 - bfu(h1));
        }
    }
    __syncthreads();                                     // B4

    // ---- mm2: h = t @ Wf2 + x @ dr_up + bf2 ----
    {
        f32x4 acc0 = {0.f, 0.f, 0.f, 0.f};
        f32x4 acc1 = {0.f, 0.f, 0.f, 0.f};
        #pragma unroll
        for (int ks = 0; ks < 4; ++ks) {
            const int aoff = l15 * 136 + ks * 32 + kl * 8;
            const bf16x8 th = *(const bf16x8*)&s_th[aoff];
            const bf16x8 tl = *(const bf16x8*)&s_tl[aoff];
            const int bo0 = (ks * 8 + nt0) * 512 + lane * 8;
            const int bo1 = (ks * 8 + nt1) * 512 + lane * 8;
            const bf16x8 bh0 = *(const bf16x8*)&pk[WF2H + bo0];
            const bf16x8 bl0 = *(const bf16x8*)&pk[WF2L + bo0];
            const bf16x8 bh1 = *(const bf16x8*)&pk[WF2H + bo1];
            const bf16x8 bl1 = *(const bf16x8*)&pk[WF2L + bo1];
            acc0 = MFMA16(th, bh0, acc0);
            acc0 = MFMA16(tl, bh0, acc0);
            acc0 = MFMA16(th, bl0, acc0);
            acc1 = MFMA16(th, bh1, acc1);
            acc1 = MFMA16(tl, bh1, acc1);
            acc1 = MFMA16(th, bl1, acc1);
        }
        {
            float x8[8] = {xv0.x, xv0.y, xv0.z, xv0.w,
                           xv1.x, xv1.y, xv1.z, xv1.w};
            bf16x8 xh, xl;
            split8(x8, xh, xl);
            const bf16x8 dh0 = *(const bf16x8*)&pk[DRH + nt0 * 512 + lane * 8];
            const bf16x8 dl0 = *(const bf16x8*)&pk[DRL + nt0 * 512 + lane * 8];
            const bf16x8 dh1 = *(const bf16x8*)&pk[DRH + nt1 * 512 + lane * 8];
            const bf16x8 dl1 = *(const bf16x8*)&pk[DRL + nt1 * 512 + lane * 8];
            acc0 = MFMA16(xh, dh0, acc0);
            acc0 = MFMA16(xl, dh0, acc0);
            acc0 = MFMA16(xh, dl0, acc0);
            acc1 = MFMA16(xh, dh1, acc1);
            acc1 = MFMA16(xl, dh1, acc1);
            acc1 = MFMA16(xh, dl1, acc1);
        }
        const float bA = bf2[nA], bB = bf2[nB];
        // pack into s_ho (s_hh region; dead since B4), then coalesced store
        #pragma unroll
        for (int r = 0; r < 4; ++r) {
            const int m = kl * 4 + r;
            s_ho[m * 128 + nA] = f2bf(acc0[r] + bA);
            s_ho[m * 128 + nB] = f2bf(acc1[r] + bB);
        }
    }
    __syncthreads();                                     // B5
    {
        const size_t base = (size_t)n0 * H;              // u16 elements
        *(uint4*)&h_out[base + t * 8] = *(const uint4*)&s_ho[t * 8];
    }
}

// ---------------------------------------------------------------------------
// CSR build (unchanged multi-block scan).
// ---------------------------------------------------------------------------
#define SCAN_B  256
#define SCAN_NB ((N_NODES + SCAN_B - 1) / SCAN_B)   // 196

__global__ __launch_bounds__(256) void k_count(
    const int* __restrict__ ei, int* __restrict__ deg)
{
    const int e = blockIdx.x * 256 + threadIdx.x;
    if (e >= E_EDGES) return;
    atomicAdd(&deg[ei[E_EDGES + e]], 1);
}

__global__ __launch_bounds__(256) void k_scanA(
    const int* __restrict__ deg, int* __restrict__ partial)
{
    const int b = blockIdx.x;
    const int t = threadIdx.x;
    const int i = b * SCAN_B + t;
    int v = (i < N_NODES) ? deg[i] : 0;
    #pragma unroll
    for (int s = 1; s < 64; s <<= 1) v += __shfl_xor(v, s);
    __shared__ int s_w[4];
    if ((t & 63) == 0) s_w[t >> 6] = v;
    __syncthreads();
    if (t == 0) partial[b] = s_w[0] + s_w[1] + s_w[2] + s_w[3];
}

__global__ __launch_bounds__(256) void k_scanB(
    int* __restrict__ partial)
{
    const int t = threadIdx.x;
    __shared__ int ss[256];
    const int v = (t < SCAN_NB) ? partial[t] : 0;
    ss[t] = v;
    __syncthreads();
    #pragma unroll
    for (int d = 1; d < 256; d <<= 1) {
        const int u = (t >= d) ? ss[t - d] : 0;
        __syncthreads();
        ss[t] += u;
        __syncthreads();
    }
    if (t < SCAN_NB) partial[t] = ss[t] - v;     // exclusive prefix of sums
}

__global__ __launch_bounds__(256) void k_scanC(
    const int* __restrict__ partial,
    int* __restrict__ off, int* __restrict__ cursor)
{
    const int b = blockIdx.x;
    const int t = threadIdx.x;
    const int i = b * SCAN_B + t;
    const int v = (i < N_NODES) ? off[i] : 0;    // off still holds degrees
    __shared__ int ss[256];
    ss[t] = v;
    __syncthreads();
    #pragma unroll
    for (int d = 1; d < 256; d <<= 1) {
        const int u = (t >= d) ? ss[t - d] : 0;
        __syncthreads();
        ss[t] += u;
        __syncthreads();
    }
    const int excl = ss[t] - v + partial[b];
    if (i < N_NODES) { off[i] = excl; cursor[i] = excl; }
    if (b == 0 && t == 0) off[N_NODES] = E_EDGES;
}

__global__ __launch_bounds__(256) void k_fill(
    const int* __restrict__ ei, const float* __restrict__ ea,
    int* __restrict__ cursor, int2* __restrict__ csr)
{
    const int e = blockIdx.x * 256 + threadIdx.x;
    if (e >= E_EDGES) return;
    const int dst = ei[E_EDGES + e];
    const int pos = atomicAdd(&cursor[dst], 1);
    csr[pos] = make_int2(ei[e], __float_as_int(ea[e]));
}

// ---------------------------------------------------------------------------
// k_layer: NPB=16 split-bf16 MFMA node update (unchanged from R9).
// ---------------------------------------------------------------------------
#define NPB 16
__global__ __launch_bounds__(256) void k_layer(
    const int* __restrict__ off, const int2* __restrict__ csr,
    const u16* __restrict__ h_in, u16* __restrict__ h_out,
    const float* __restrict__ ew, const float* __restrict__ eb,
    const float* __restrict__ eps_p,
    const u16* __restrict__ wh1, const u16* __restrict__ wl1,
    const float* __restrict__ b1, const float* __restrict__ bn_g,
    const float* __restrict__ bn_b, const float* __restrict__ bn_m,
    const float* __restrict__ bn_v,
    const u16* __restrict__ wh2, const u16* __restrict__ wl2,
    const float* __restrict__ b2,
    const int first_layer, const int last_layer,
    const float* __restrict__ aw, const float* __restrict__ ab,
    float* __restrict__ out)
{
    const int n0 = blockIdx.x * NPB;
    const int t  = threadIdx.x;

    __shared__ __align__(16) u16   s_pool[2 * 16 * 136];
    __shared__ __align__(16) u16   s_th[16 * 136];
    __shared__ __align__(16) u16   s_tl[16 * 136];
    __shared__ __align__(16) float s_r [16 * 128];
    u16* s_zh = s_pool;
    u16* s_zl = s_pool + 16 * 136;
    float* s_hd = (float*)s_pool;

    const float ep1 = 1.f + eps_p[0];

    // ---- phase 1: gather. quarter-wave (16 lanes) owns one node ----
    {
        const int q = t >> 4;            // node slot 0..15
        const int c = (t & 15) * 8;      // channel base (8 ch/lane)
        const int n = n0 + q;

        const float4 wv0 = *(const float4*)&ew[c];
        const float4 wv1 = *(const float4*)&ew[c + 4];
        const float4 bv0 = *(const float4*)&eb[c];
        const float4 bv1 = *(const float4*)&eb[c + 4];

        int i        = off[n];
        const int hi = off[n + 1];

        float a0[8], a1[8];
        #pragma unroll
        for (int j = 0; j < 8; ++j) { a0[j] = 0.f; a1[j] = 0.f; }

        int2 p[8];
        bool have = (i + 7 < hi);
        if (have) {
            #pragma unroll
            for (int u = 0; u < 8; ++u) p[u] = csr[i + u];
        }
        while (have) {
            uint4 hq[8];
            #pragma unroll
            for (int u = 0; u < 8; ++u)
                hq[u] = *(const uint4*)&h_in[(size_t)p[u].x * H + c];

            const int inext = i + 8;
            const bool more = (inext + 7 < hi);

            #pragma unroll
            for (int u = 0; u < 8; ++u) {
                const float a = __int_as_float(p[u].y);
                const float h0 = bf_lo(hq[u].x), h1 = bf_hi(hq[u].x);
                const float h2 = bf_lo(hq[u].y), h3 = bf_hi(hq[u].y);
                const float h4 = bf_lo(hq[u].z), h5 = bf_hi(hq[u].z);
                const float h6 = bf_lo(hq[u].w), h7 = bf_hi(hq[u].w);
                float* acc = (u & 1) ? a1 : a0;
                acc[0] += fmaxf(fmaf(a, wv0.x, h0) + bv0.x, 0.f);
                acc[1] += fmaxf(fmaf(a, wv0.y, h1) + bv0.y, 0.f);
                acc[2] += fmaxf(fmaf(a, wv0.z, h2) + bv0.z, 0.f);
                acc[3] += fmaxf(fmaf(a, wv0.w, h3) + bv0.w, 0.f);
                acc[4] += fmaxf(fmaf(a, wv1.x, h4) + bv1.x, 0.f);
                acc[5] += fmaxf(fmaf(a, wv1.y, h5) + bv1.y, 0.f);
                acc[6] += fmaxf(fmaf(a, wv1.z, h6) + bv1.z, 0.f);
                acc[7] += fmaxf(fmaf(a, wv1.w, h7) + bv1.w, 0.f);
            }
            if (more) {
                #pragma unroll
                for (int u = 0; u < 8; ++u) p[u] = csr[inext + u];
            }
            i = inext;
            have = more;
        }
        for (; i < hi; ++i) {
            const int2 p0 = csr[i];
            const uint4 hq = *(const uint4*)&h_in[(size_t)p0.x * H + c];
            const float a = __int_as_float(p0.y);
            a0[0] += fmaxf(fmaf(a, wv0.x, bf_lo(hq.x)) + bv0.x, 0.f);
            a0[1] += fmaxf(fmaf(a, wv0.y, bf_hi(hq.x)) + bv0.y, 0.f);
            a0[2] += fmaxf(fmaf(a, wv0.z, bf_lo(hq.y)) + bv0.z, 0.f);
            a0[3] += fmaxf(fmaf(a, wv0.w, bf_hi(hq.y)) + bv0.w, 0.f);
            a0[4] += fmaxf(fmaf(a, wv1.x, bf_lo(hq.z)) + bv1.x, 0.f);
            a0[5] += fmaxf(fmaf(a, wv1.y, bf_hi(hq.z)) + bv1.y, 0.f);
            a0[6] += fmaxf(fmaf(a, wv1.z, bf_lo(hq.w)) + bv1.z, 0.f);
            a0[7] += fmaxf(fmaf(a, wv1.w, bf_hi(hq.w)) + bv1.w, 0.f);
        }
        #pragma unroll
        for (int j = 0; j < 8; ++j) a0[j] += a1[j];

        const uint4 ho = *(const uint4*)&h_in[(size_t)n * H + c];
        const float r0 = bf_lo(ho.x), r1 = bf_hi(ho.x);
        const float r2 = bf_lo(ho.y), r3 = bf_hi(ho.y);
        const float r4 = bf_lo(ho.z), r5 = bf_hi(ho.z);
        const float r6 = bf_lo(ho.w), r7 = bf_hi(ho.w);
        *(float4*)&s_r[q * 128 + c]     = make_float4(r0, r1, r2, r3);
        *(float4*)&s_r[q * 128 + c + 4] = make_float4(r4, r5, r6, r7);

        const float rr[8] = {r0, r1, r2, r3, r4, r5, r6, r7};
        #pragma unroll
        for (int k = 0; k < 4; ++k) {
            const float za = fmaf(ep1, rr[2*k],   a0[2*k]);
            const float zb = fmaf(ep1, rr[2*k+1], a0[2*k+1]);
            const u16 zha = f2bf(za), zhb = f2bf(zb);
            *(u32*)&s_zh[q * 136 + c + 2*k] = (u32)zha | ((u32)zhb << 16);
            *(u32*)&s_zl[q * 136 + c + 2*k] =
                pack2bf(za - bfu(zha), zb - bfu(zhb));
        }
    }
    __syncthreads();

    const int lane = t & 63;
    const int wv   = t >> 6;
    const int l15  = lane & 15;
    const int kl   = lane >> 4;
    const int nt0  = wv * 2, nt1 = wv * 2 + 1;
    const int nA   = nt0 * 16 + l15;
    const int nB   = nt1 * 16 + l15;

    // ---- phase 2: t = relu(BN(z @ w1 + b1))  [MFMA, 16 real rows] ----
    {
        f32x4 acc0 = {0.f, 0.f, 0.f, 0.f};
        f32x4 acc1 = {0.f, 0.f, 0.f, 0.f};
        #pragma unroll
        for (int ks = 0; ks < 4; ++ks) {
            const int aoff = l15 * 136 + ks * 32 + kl * 8;
            const bf16x8 ah = *(const bf16x8*)&s_zh[aoff];
            const bf16x8 al = *(const bf16x8*)&s_zl[aoff];
            const int bo0 = (ks * 8 + nt0) * 512 + lane * 8;
            const int bo1 = (ks * 8 + nt1) * 512 + lane * 8;
            const bf16x8 bh0 = *(const bf16x8*)&wh1[bo0];
            const bf16x8 bl0 = *(const bf16x8*)&wl1[bo0];
            const bf16x8 bh1 = *(const bf16x8*)&wh1[bo1];
            const bf16x8 bl1 = *(const bf16x8*)&wl1[bo1];
            acc0 = MFMA16(ah, bh0, acc0);
            acc0 = MFMA16(al, bh0, acc0);
            acc0 = MFMA16(ah, bl0, acc0);
            acc1 = MFMA16(ah, bh1, acc1);
            acc1 = MFMA16(al, bh1, acc1);
            acc1 = MFMA16(ah, bl1, acc1);
        }
        const float sc0 = bn_g[nA] * rsqrtf(bn_v[nA] + BN_EPS);
        const float sh0 = fmaf(b1[nA] - bn_m[nA], sc0, bn_b[nA]);
        const float sc1 = bn_g[nB] * rsqrtf(bn_v[nB] + BN_EPS);
        const float sh1 = fmaf(b1[nB] - bn_m[nB], sc1, bn_b[nB]);

        #pragma unroll
        for (int r = 0; r < 4; ++r) {
            const int m = kl * 4 + r;
            const float t0 = fmaxf(fmaf(acc0[r], sc0, sh0), 0.f);
            const float t1 = fmaxf(fmaf(acc1[r], sc1, sh1), 0.f);
            const u16 th0 = f2bf(t0), th1 = f2bf(t1);
            s_th[m * 136 + nA] = th0;
            s_tl[m * 136 + nA] = f2bf(t0 - bfu(th0));
            s_th[m * 136 + nB] = th1;
            s_tl[m * 136 + nB] = f2bf(t1 - bfu(th1));
        }
    }
    __syncthreads();

    // ---- phase 3: c = t @ w2 + b2; h' = relu(c) (+res); store / head ----
    {
        f32x4 acc0 = {0.f, 0.f, 0.f, 0.f};
        f32x4 acc1 = {0.f, 0.f, 0.f, 0.f};
        #pragma unroll
        for (int ks = 0; ks < 4; ++ks) {
            const int aoff = l15 * 136 + ks * 32 + kl * 8;
            const bf16x8 ah = *(const bf16x8*)&s_th[aoff];
            const bf16x8 al = *(const bf16x8*)&s_tl[aoff];
            const int bo0 = (ks * 8 + nt0) * 512 + lane * 8;
            const int bo1 = (ks * 8 + nt1) * 512 + lane * 8;
            const bf16x8 bh0 = *(const bf16x8*)&wh2[bo0];
            const bf16x8 bl0 = *(const bf16x8*)&wl2[bo0];
            const bf16x8 bh1 = *(const bf16x8*)&wh2[bo1];
            const bf16x8 bl1 = *(const bf16x8*)&wl2[bo1];
            acc0 = MFMA16(ah, bh0, acc0);
            acc0 = MFMA16(al, bh0, acc0);
            acc0 = MFMA16(ah, bl0, acc0);
            acc1 = MFMA16(ah, bh1, acc1);
            acc1 = MFMA16(al, bh1, acc1);
            acc1 = MFMA16(ah, bl1, acc1);
        }
        const float bb0 = b2[nA];
        const float bb1 = b2[nB];

        float hv0[4], hv1[4];
        #pragma unroll
        for (int r = 0; r < 4; ++r) {
            const int m = kl * 4 + r;
            hv0[r] = fmaxf(acc0[r] + bb0, 0.f);
            hv1[r] = fmaxf(acc1[r] + bb1, 0.f);
            if (!first_layer) {
                hv0[r] += s_r[m * 128 + nA];
                hv1[r] += s_r[m * 128 + nB];
            }
        }

        if (!last_layer) {
            // coalesced store: pack bf16 into reused s_th, then 16B/thread
            __syncthreads();                     // all s_th/s_tl reads done
            u16* s_ho = s_th;                    // 16 x 128 u16 = 4 KB
            #pragma unroll
            for (int r = 0; r < 4; ++r) {
                const int m = kl * 4 + r;
                s_ho[m * 128 + nA] = f2bf(hv0[r]);
                s_ho[m * 128 + nB] = f2bf(hv1[r]);
            }
            __syncthreads();
            const size_t base = (size_t)n0 * H;  // u16 elements
            *(uint4*)&h_out[base + t * 8] = *(const uint4*)&s_ho[t * 8];
        } else {
            #pragma unroll
            for (int r = 0; r < 4; ++r) {
                const int m = kl * 4 + r;
                s_hd[m * 128 + nA] = hv0[r];
                s_hd[m * 128 + nB] = hv1[r];
            }
        }
    }

    if (last_layer) {
        __syncthreads();
        const int q = t >> 4;
        const int c = (t & 15) * 8;
        float mu = 0.f, sg = 0.f;
        #pragma unroll
        for (int j = 0; j < 8; ++j) {
            const float hv = s_hd[q * 128 + c + j];
            const float2 awj = *(const float2*)&aw[(c + j) * 2];
            mu = fmaf(hv, awj.x, mu);
            sg = fmaf(hv, awj.y, sg);
        }
        #pragma unroll
        for (int s = 1; s < 16; s <<= 1) {
            mu += __shfl_xor(mu, s);
            sg += __shfl_xor(sg, s);
        }
        if ((t & 15) == 0) {
            const float o1 = sg + ab[1];
            const float sp = (o1 > 0.f) ? (o1 + log1pf(expf(-o1)))
                                        : log1pf(expf(o1));
            out[(size_t)(n0 + q) * 2 + 0] = mu + ab[0];
            out[(size_t)(n0 + q) * 2 + 1] = sp;
        }
    }
}

// ---------------------------------------------------------------------------
extern "C" void kernel_launch(void* const* d_in, const int* in_sizes, int n_in,
                              void* d_out, int out_size, void* d_ws, size_t ws_size,
                              hipStream_t stream)
{
    const float* ensemble = (const float*)d_in[0];
    const float* x        = (const float*)d_in[1];
    const int*   ei       = (const int*)d_in[2];
    const float* ea       = (const float*)d_in[3];
    const float* phi_w1   = (const float*)d_in[4];
    const float* phi_b1   = (const float*)d_in[5];
    const float* phi_w2   = (const float*)d_in[6];
    const float* phi_b2   = (const float*)d_in[7];
    const float* rho_w1   = (const float*)d_in[8];
    const float* rho_b1   = (const float*)d_in[9];
    const float* rho_w2   = (const float*)d_in[10];
    const float* rho_b2   = (const float*)d_in[11];
    const float* dr_w     = (const float*)d_in[12];
    const float* dr_b     = (const float*)d_in[13];
    const float* conv_eps = (const float*)d_in[14];
    const float* edge_w   = (const float*)d_in[15];
    const float* edge_b   = (const float*)d_in[16];
    const float* mlp_w1   = (const float*)d_in[17];
    const float* mlp_b1   = (const float*)d_in[18];
    const float* bn_g     = (const float*)d_in[19];
    const float* bn_b     = (const float*)d_in[20];
    const float* bn_m     = (const float*)d_in[21];
    const float* bn_v     = (const float*)d_in[22];
    const float* mlp_w2   = (const float*)d_in[23];
    const float* mlp_b2   = (const float*)d_in[24];
    const float* aggr_w   = (const float*)d_in[25];
    const float* aggr_b   = (const float*)d_in[26];

    float* out = (float*)d_out;

    // workspace layout — R2 footprint + 1 KB scan partials.
    float* Wf1     = (float*)d_ws;                          // H*H
    float* bf1     = Wf1 + H * H;                           // H
    float* Wf2     = bf1 + H;                               // H*H
    float* bf2     = Wf2 + H * H;                           // H
    int*   off     = (int*)(bf2 + H);                       // N+2 (padded)
    int*   cursor  = off + (N_NODES + 2);                   // N
    int2*  csr     = (int2*)(cursor + N_NODES);             // E (8B aligned)
    u16*   h_a     = (u16*)(csr + E_EDGES);                 // N*H bf16
    u16*   h_b     = h_a + (size_t)N_NODES * H;             // N*H bf16
    u16*   wpk     = h_b + (size_t)N_NODES * H;             // 196608 u16
    u16*   wpk2    = wpk + 196608;                          // 81920 u16
    int*   partial = (int*)(wpk2 + 81920);                  // SCAN_NB ints

    const int eblocks = (E_EDGES + 255) / 256;

    // fold weights, pack MFMA weights
    k_fold<<<256, 256, 0, stream>>>(phi_w2, phi_b2, rho_w1, rho_b1,
                                    rho_w2, rho_b2, dr_w, dr_b,
                                    Wf1, bf1, Wf2, bf2);
    k_pack<<<384, 256, 0, stream>>>(mlp_w1, mlp_w2, wpk);
    k_pack2<<<160, 256, 0, stream>>>(phi_w1, Wf1, Wf2, dr_w, wpk2);

    // embed: fused phi + matmul chain -> h_a
    k_embed<<<N_NODES / 16, 256, 0, stream>>>(
        ensemble, x, phi_b1, bf1, bf2, wpk2, h_a);

    // CSR build (once) — multi-block scan
    hipMemsetAsync(off, 0, (N_NODES + 1) * sizeof(int), stream);
    k_count<<<eblocks, 256, 0, stream>>>(ei, off);
    k_scanA<<<SCAN_NB, 256, 0, stream>>>(off, partial);
    k_scanB<<<1, 256, 0, stream>>>(partial);
    k_scanC<<<SCAN_NB, 256, 0, stream>>>(partial, off, cursor);
    k_fill<<<eblocks, 256, 0, stream>>>(ei, ea, cursor, csr);

    // fused GINE layers (double-buffered h; last layer writes head to out)
    u16* hin = h_a; u16* hout = h_b;
    for (int i = 0; i < L_LAYERS; ++i) {
        const u16* wh1 = wpk + ((size_t)i * 2 + 0) * 32768;
        const u16* wl1 = wh1 + 16384;
        const u16* wh2 = wpk + ((size_t)i * 2 + 1) * 32768;
        const u16* wl2 = wh2 + 16384;
        k_layer<<<N_NODES / NPB, 256, 0, stream>>>(
            off, csr, hin, hout,
            edge_w + (size_t)i * H, edge_b + (size_t)i * H, conv_eps + i,
            wh1, wl1,
            mlp_b1 + (size_t)i * H,
            bn_g + (size_t)i * H, bn_b + (size_t)i * H,
            bn_m + (size_t)i * H, bn_v + (size_t)i * H,
            wh2, wl2, mlp_b2 + (size_t)i * H,
            (i == 0) ? 1 : 0, (i == L_LAYERS - 1) ? 1 : 0,
            aggr_w, aggr_b, out);
        u16* tmp = hin; hin = hout; hout = tmp;
    }
}

// Round 11
// 544.510 us; speedup vs baseline: 1.0264x; 1.0264x over previous
//
#include <hip/hip_runtime.h>
#include <math.h>

#define N_NODES 50000
#define M_ENS   20
#define C_IN    32
#define H       128
#define E_EDGES 800000
#define L_LAYERS 3
#define BN_EPS  1e-5f

typedef unsigned short u16;
typedef unsigned int   u32;

typedef __attribute__((ext_vector_type(8))) short bf16x8;  // 8 bf16 = 4 VGPR
typedef __attribute__((ext_vector_type(4))) float f32x4;

#define MFMA16(a, b, c) __builtin_amdgcn_mfma_f32_16x16x32_bf16((a), (b), (c), 0, 0, 0)

// bf16 helpers (RNE pack, cheap unpack)
__device__ __forceinline__ float bf_lo(u32 p) {
    union { u32 u; float f; } v; v.u = p << 16; return v.f;
}
__device__ __forceinline__ float bf_hi(u32 p) {
    union { u32 u; float f; } v; v.u = p & 0xFFFF0000u; return v.f;
}
__device__ __forceinline__ u16 f2bf(float f) {
    union { float f; u32 u; } v; v.f = f;
    const u32 r = v.u + 0x7FFFu + ((v.u >> 16) & 1u);
    return (u16)(r >> 16);
}
__device__ __forceinline__ float bfu(u16 h) {
    union { u32 u; float f; } v; v.u = (u32)h << 16; return v.f;
}
__device__ __forceinline__ u32 pack2bf(float a, float b) {
    return (u32)f2bf(a) | ((u32)f2bf(b) << 16);
}

// split f32[8] -> (hi, lo) bf16x8 fragments
__device__ __forceinline__ void split8(const float* a, bf16x8& h, bf16x8& l) {
    #pragma unroll
    for (int j = 0; j < 8; ++j) {
        const u16 hv = f2bf(a[j]);
        h[j] = (short)hv;
        l[j] = (short)f2bf(a[j] - bfu(hv));
    }
}

// ---------------------------------------------------------------------------
// k_fold: precompute folded weights (unchanged).
// ---------------------------------------------------------------------------
__global__ __launch_bounds__(256) void k_fold(
    const float* __restrict__ w2,  const float* __restrict__ b2,
    const float* __restrict__ rw1, const float* __restrict__ rb1,
    const float* __restrict__ rw2, const float* __restrict__ rb2,
    const float* __restrict__ dr_w, const float* __restrict__ dr_b,
    float* __restrict__ Wf1, float* __restrict__ bf1,
    float* __restrict__ Wf2, float* __restrict__ bf2)
{
    const int g = blockIdx.x >> 7;
    const int j = blockIdx.x & 127;
    const int t = threadIdx.x;

    const float* A  = g ? rw2 : w2;
    const float* Bm = g ? (dr_w + C_IN * H) : rw1;

    __shared__ float s_col[H];
    if (t < H) s_col[t] = Bm[t * H + j];
    __syncthreads();

    const int r = t >> 1, q = t & 1;
    const float* arow = &A[r * H + q * 64];
    const float* cp = &s_col[q * 64];
    float acc = 0.f;
    #pragma unroll
    for (int u = 0; u < 64; u += 4) {
        const float4 av = *(const float4*)&arow[u];
        acc = fmaf(av.x, cp[u], acc);
        acc = fmaf(av.y, cp[u + 1], acc);
        acc = fmaf(av.z, cp[u + 2], acc);
        acc = fmaf(av.w, cp[u + 3], acc);
    }
    acc += __shfl_xor(acc, 1);
    if (q == 0) (g ? Wf2 : Wf1)[r * H + j] = acc;

    if (t == 0) {
        float bacc = g ? dr_b[j] : rb1[j];
        const float* bsrc = g ? rb2 : b2;
        const float scale = g ? 1.f : 20.f;
        for (int k = 0; k < H; ++k)
            bacc = fmaf(scale * bsrc[k], s_col[k], bacc);
        (g ? bf2 : bf1)[j] = bacc;
    }
}

// ---------------------------------------------------------------------------
// k_pack: repack mlp_w1/mlp_w2 into MFMA B-fragment order, split-bf16 (hi/lo).
// ---------------------------------------------------------------------------
__global__ __launch_bounds__(256) void k_pack(
    const float* __restrict__ w1, const float* __restrict__ w2,
    u16* __restrict__ wpk)
{
    const int tid = blockIdx.x * 256 + threadIdx.x;   // 3*2*4*8*64*8 = 98304
    const int j    = tid & 7;
    const int lane = (tid >> 3) & 63;
    const int nt   = (tid >> 9) & 7;
    const int ks   = (tid >> 12) & 3;
    const int mat  = (tid >> 14) & 1;
    const int l    = tid >> 15;
    if (l >= L_LAYERS) return;

    const int k = ks * 32 + (lane >> 4) * 8 + j;
    const int n = nt * 16 + (lane & 15);
    const float* w = (mat ? w2 : w1) + (size_t)l * H * H;
    const float v = w[k * H + n];

    const u16 hi = f2bf(v);
    const float lo = v - bfu(hi);

    u16* base = wpk + ((size_t)(l * 2 + mat)) * 32768;   // 2 parts * 16384
    const int idx = (ks * 8 + nt) * 512 + lane * 8 + j;
    base[idx] = hi;
    base[16384 + idx] = f2bf(lo);
}

// ---------------------------------------------------------------------------
// k_pack2: pack embed-path weights into MFMA B-fragment order, split hi/lo.
// ---------------------------------------------------------------------------
#define PW1H 0
#define PW1L 4096
#define WF1H 8192
#define WF1L 24576
#define WF2H 40960
#define WF2L 57344
#define DRH  73728
#define DRL  77824
__global__ __launch_bounds__(256) void k_pack2(
    const float* __restrict__ phi_w1, const float* __restrict__ Wf1,
    const float* __restrict__ Wf2,    const float* __restrict__ dr_w,
    u16* __restrict__ pk)
{
    const int tid = blockIdx.x * 256 + threadIdx.x;   // 40960 total
    int idx; const float* src; int bh; int bl;
    if (tid < 4096)       { idx = tid;         src = phi_w1; bh = PW1H; bl = PW1L; }
    else if (tid < 20480) { idx = tid - 4096;  src = Wf1;    bh = WF1H; bl = WF1L; }
    else if (tid < 36864) { idx = tid - 20480; src = Wf2;    bh = WF2H; bl = WF2L; }
    else if (tid < 40960) { idx = tid - 36864; src = dr_w;   bh = DRH;  bl = DRL;  }
    else return;

    const int j    = idx & 7;
    const int lane = (idx >> 3) & 63;
    const int nt   = (idx >> 9) & 7;
    const int ks   = idx >> 12;
    const int k = ks * 32 + (lane >> 4) * 8 + j;
    const int n = nt * 16 + (lane & 15);
    const float v = src[k * H + n];
    const u16 hi = f2bf(v);
    pk[bh + idx] = hi;
    pk[bl + idx] = f2bf(v - bfu(hi));
}

// ---------------------------------------------------------------------------
// k_phi v4 (R9, reverted): coalesced staging + coalesced plane stores.
// ---------------------------------------------------------------------------
__global__ __launch_bounds__(256) void k_phi(
    const float* __restrict__ ensemble, const float* __restrict__ phi_b1,
    const u16* __restrict__ pk,
    u16* __restrict__ hh, u16* __restrict__ hl)
{
    const int n0 = blockIdx.x * 16;
    const int t  = threadIdx.x;
    const int lane = t & 63;
    const int w    = t >> 6;
    const int l15  = lane & 15;
    const int kl   = lane >> 4;

    __shared__ __align__(16) char s_ens[16 * M_ENS * C_IN * 4];   // 40960 B

    // ---- stage: linear coalesced loads into registers ----
    const char* gsrc = (const char*)(ensemble + (size_t)n0 * (M_ENS * C_IN));
    float4 st[10];
    #pragma unroll
    for (int it = 0; it < 10; ++it)
        st[it] = *(const float4*)(gsrc + it * 4096 + w * 1024 + lane * 16);

    // phi B fragments + bias while the loads are in flight
    bf16x8 pbh[8], pbl[8];
    #pragma unroll
    for (int nt = 0; nt < 8; ++nt) {
        pbh[nt] = *(const bf16x8*)&pk[PW1H + nt * 512 + lane * 8];
        pbl[nt] = *(const bf16x8*)&pk[PW1L + nt * 512 + lane * 8];
    }
    float b1v[8];
    #pragma unroll
    for (int nt = 0; nt < 8; ++nt) b1v[nt] = phi_b1[nt * 16 + l15];

    // ---- swizzled LDS writes ----
    #pragma unroll
    for (int it = 0; it < 10; ++it) {
        const int o   = it * 4096 + w * 1024 + lane * 16;
        const int row = o >> 7;
        *(float4*)(s_ens + (o ^ ((row & 7) << 4))) = st[it];
    }
    __syncthreads();

    float acc[4][8];
    #pragma unroll
    for (int r = 0; r < 4; ++r)
        #pragma unroll
        for (int nt = 0; nt < 8; ++nt) acc[r][nt] = 0.f;

    #pragma unroll
    for (int tt = 0; tt < 5; ++tt) {
        const int node = w * 4 + (l15 & 3);
        const int row  = node * M_ENS + (l15 >> 2) * 5 + tt;
        const int a0   = row * 128 + kl * 32;
        const int s0   = a0 ^ ((row & 7) << 4);
        const float4 v0 = *(const float4*)(s_ens + s0);
        const float4 v1 = *(const float4*)(s_ens + (s0 ^ 16));
        float a8[8] = {v0.x, v0.y, v0.z, v0.w, v1.x, v1.y, v1.z, v1.w};
        bf16x8 ah, al;
        split8(a8, ah, al);
        #pragma unroll
        for (int nt = 0; nt < 8; ++nt) {
            f32x4 c = {0.f, 0.f, 0.f, 0.f};
            c = MFMA16(ah, pbh[nt], c);
            c = MFMA16(al, pbh[nt], c);
            c = MFMA16(ah, pbl[nt], c);
            #pragma unroll
            for (int r = 0; r < 4; ++r)
                acc[r][nt] += fmaxf(c[r] + b1v[nt], 0.f);
        }
    }

    // m-sum across the 4 kl groups (each holds 5 of the 20 members)
    #pragma unroll
    for (int r = 0; r < 4; ++r)
        #pragma unroll
        for (int nt = 0; nt < 8; ++nt) {
            float v = acc[r][nt];
            v += __shfl_xor(v, 16);
            v += __shfl_xor(v, 32);
            acc[r][nt] = v;
        }

    // ---- plane stores: LDS pack + coalesced copy-out ----
    __syncthreads();                    // all fragment reads of s_ens done
    u16* s_hh = (u16*)s_ens;            // 16 x 128 u16 = 4 KB
    u16* s_hl = (u16*)(s_ens + 4096);   // 16 x 128 u16 = 4 KB
    #pragma unroll
    for (int r = 0; r < 4; ++r) {
        if (kl == r) {
            const int node = w * 4 + r;
            #pragma unroll
            for (int nt = 0; nt < 8; ++nt) {
                const float v = acc[r][nt];
                const u16 hv = f2bf(v);
                s_hh[node * 128 + nt * 16 + l15] = hv;
                s_hl[node * 128 + nt * 16 + l15] = f2bf(v - bfu(hv));
            }
        }
    }
    __syncthreads();
    {
        const size_t base = (size_t)n0 * H;         // u16 elements
        *(uint4*)&hh[base + t * 8] = *(const uint4*)&s_hh[t * 8];
        *(uint4*)&hl[base + t * 8] = *(const uint4*)&s_hl[t * 8];
    }
}

// ---------------------------------------------------------------------------
// k_emb2 v2 (R9, reverted): A-frags staged through LDS.
// ALIAS SAFETY (hl == h_out == h_a): all hl reads consumed into LDS before
// the first __syncthreads(); all h_out stores after the second. Not
// __restrict__ on the aliased pointers.
// ---------------------------------------------------------------------------
__global__ __launch_bounds__(256) void k_emb2(
    const float* __restrict__ x,
    const u16* __restrict__ hh, const u16* hl,
    const float* __restrict__ bf1, const float* __restrict__ bf2,
    const u16* __restrict__ pk,
    u16* h_out)
{
    const int n0 = blockIdx.x * 16;
    const int t  = threadIdx.x;
    const int lane = t & 63;
    const int w    = t >> 6;
    const int l15  = lane & 15;
    const int kl   = lane >> 4;
    const int nt0  = w * 2, nt1 = nt0 + 1;
    const int nA   = nt0 * 16 + l15, nB = nt1 * 16 + l15;

    __shared__ __align__(16) u16 s_hh[16 * 128], s_hl[16 * 128];
    __shared__ __align__(16) u16 s_th[16 * 136], s_tl[16 * 136];

    // ---- coalesced stage of hh/hl rows (swizzled dest) ----
    {
        const size_t base = (size_t)n0 * H;         // u16 elements
        const int o  = t * 16;                       // byte offset 0..4080
        const int sw = o ^ (((o >> 8) & 7) << 4);
        *(uint4*)((char*)s_hh + sw) =
            *(const uint4*)((const char*)(hh + base) + o);
        *(uint4*)((char*)s_hl + sw) =
            *(const uint4*)((const char*)(hl + base) + o);
    }
    const float* xb = x + (size_t)(n0 + l15) * C_IN + kl * 8;
    const float4 xv0 = *(const float4*)xb;
    const float4 xv1 = *(const float4*)(xb + 4);
    __syncthreads();

    // fragment reads (swizzled): row = l15 (256 B), byte a = row*256+ks*64+kl*16
    bf16x8 ah[4], al[4];
    #pragma unroll
    for (int ks = 0; ks < 4; ++ks) {
        const int a  = l15 * 256 + ks * 64 + kl * 16;
        const int s  = a ^ ((l15 & 7) << 4);
        ah[ks] = *(const bf16x8*)((const char*)s_hh + s);
        al[ks] = *(const bf16x8*)((const char*)s_hl + s);
    }

    // ---- mm1: t = relu(hsum @ Wf1 + bf1) ----
    {
        f32x4 acc0 = {0.f, 0.f, 0.f, 0.f};
        f32x4 acc1 = {0.f, 0.f, 0.f, 0.f};
        #pragma unroll
        for (int ks = 0; ks < 4; ++ks) {
            const int bo0 = (ks * 8 + nt0) * 512 + lane * 8;
            const int bo1 = (ks * 8 + nt1) * 512 + lane * 8;
            const bf16x8 bh0 = *(const bf16x8*)&pk[WF1H + bo0];
            const bf16x8 bl0 = *(const bf16x8*)&pk[WF1L + bo0];
            const bf16x8 bh1 = *(const bf16x8*)&pk[WF1H + bo1];
            const bf16x8 bl1 = *(const bf16x8*)&pk[WF1L + bo1];
            acc0 = MFMA16(ah[ks], bh0, acc0);
            acc0 = MFMA16(al[ks], bh0, acc0);
            acc0 = MFMA16(ah[ks], bl0, acc0);
            acc1 = MFMA16(ah[ks], bh1, acc1);
            acc1 = MFMA16(al[ks], bh1, acc1);
            acc1 = MFMA16(ah[ks], bl1, acc1);
        }
        const float bA = bf1[nA], bB = bf1[nB];
        #pragma unroll
        for (int r = 0; r < 4; ++r) {
            const int m = kl * 4 + r;
            const float t0 = fmaxf(acc0[r] + bA, 0.f);
            const float t1 = fmaxf(acc1[r] + bB, 0.f);
            const u16 h0 = f2bf(t0), h1 = f2bf(t1);
            s_th[m * 136 + nA] = h0;
            s_tl[m * 136 + nA] = f2bf(t0 - bfu(h0));
            s_th[m * 136 + nB] = h1;
            s_tl[m * 136 + nB] = f2bf(t1 - bfu(h1));
        }
    }
    __syncthreads();

    // ---- mm2: h = t @ Wf2 + x @ dr_up + bf2 ----
    {
        f32x4 acc0 = {0.f, 0.f, 0.f, 0.f};
        f32x4 acc1 = {0.f, 0.f, 0.f, 0.f};
        #pragma unroll
        for (int ks = 0; ks < 4; ++ks) {
            const int aoff = l15 * 136 + ks * 32 + kl * 8;
            const bf16x8 th = *(const bf16x8*)&s_th[aoff];
            const bf16x8 tl = *(const bf16x8*)&s_tl[aoff];
            const int bo0 = (ks * 8 + nt0) * 512 + lane * 8;
            const int bo1 = (ks * 8 + nt1) * 512 + lane * 8;
            const bf16x8 bh0 = *(const bf16x8*)&pk[WF2H + bo0];
            const bf16x8 bl0 = *(const bf16x8*)&pk[WF2L + bo0];
            const bf16x8 bh1 = *(const bf16x8*)&pk[WF2H + bo1];
            const bf16x8 bl1 = *(const bf16x8*)&pk[WF2L + bo1];
            acc0 = MFMA16(th, bh0, acc0);
            acc0 = MFMA16(tl, bh0, acc0);
            acc0 = MFMA16(th, bl0, acc0);
            acc1 = MFMA16(th, bh1, acc1);
            acc1 = MFMA16(tl, bh1, acc1);
            acc1 = MFMA16(th, bl1, acc1);
        }
        {
            float x8[8] = {xv0.x, xv0.y, xv0.z, xv0.w,
                           xv1.x, xv1.y, xv1.z, xv1.w};
            bf16x8 xh, xl;
            split8(x8, xh, xl);
            const bf16x8 dh0 = *(const bf16x8*)&pk[DRH + nt0 * 512 + lane * 8];
            const bf16x8 dl0 = *(const bf16x8*)&pk[DRL + nt0 * 512 + lane * 8];
            const bf16x8 dh1 = *(const bf16x8*)&pk[DRH + nt1 * 512 + lane * 8];
            const bf16x8 dl1 = *(const bf16x8*)&pk[DRL + nt1 * 512 + lane * 8];
            acc0 = MFMA16(xh, dh0, acc0);
            acc0 = MFMA16(xl, dh0, acc0);
            acc0 = MFMA16(xh, dl0, acc0);
            acc1 = MFMA16(xh, dh1, acc1);
            acc1 = MFMA16(xl, dh1, acc1);
            acc1 = MFMA16(xh, dl1, acc1);
        }
        const float bA = bf2[nA], bB = bf2[nB];
        #pragma unroll
        for (int r = 0; r < 4; ++r) {
            const int m = kl * 4 + r;
            h_out[(size_t)(n0 + m) * H + nA] = f2bf(acc0[r] + bA);
            h_out[(size_t)(n0 + m) * H + nB] = f2bf(acc1[r] + bB);
        }
    }
}

// ---------------------------------------------------------------------------
// CSR build (unchanged multi-block scan).
// ---------------------------------------------------------------------------
#define SCAN_B  256
#define SCAN_NB ((N_NODES + SCAN_B - 1) / SCAN_B)   // 196

__global__ __launch_bounds__(256) void k_count(
    const int* __restrict__ ei, int* __restrict__ deg)
{
    const int e = blockIdx.x * 256 + threadIdx.x;
    if (e >= E_EDGES) return;
    atomicAdd(&deg[ei[E_EDGES + e]], 1);
}

__global__ __launch_bounds__(256) void k_scanA(
    const int* __restrict__ deg, int* __restrict__ partial)
{
    const int b = blockIdx.x;
    const int t = threadIdx.x;
    const int i = b * SCAN_B + t;
    int v = (i < N_NODES) ? deg[i] : 0;
    #pragma unroll
    for (int s = 1; s < 64; s <<= 1) v += __shfl_xor(v, s);
    __shared__ int s_w[4];
    if ((t & 63) == 0) s_w[t >> 6] = v;
    __syncthreads();
    if (t == 0) partial[b] = s_w[0] + s_w[1] + s_w[2] + s_w[3];
}

__global__ __launch_bounds__(256) void k_scanB(
    int* __restrict__ partial)
{
    const int t = threadIdx.x;
    __shared__ int ss[256];
    const int v = (t < SCAN_NB) ? partial[t] : 0;
    ss[t] = v;
    __syncthreads();
    #pragma unroll
    for (int d = 1; d < 256; d <<= 1) {
        const int u = (t >= d) ? ss[t - d] : 0;
        __syncthreads();
        ss[t] += u;
        __syncthreads();
    }
    if (t < SCAN_NB) partial[t] = ss[t] - v;     // exclusive prefix of sums
}

__global__ __launch_bounds__(256) void k_scanC(
    const int* __restrict__ partial,
    int* __restrict__ off, int* __restrict__ cursor)
{
    const int b = blockIdx.x;
    const int t = threadIdx.x;
    const int i = b * SCAN_B + t;
    const int v = (i < N_NODES) ? off[i] : 0;    // off still holds degrees
    __shared__ int ss[256];
    ss[t] = v;
    __syncthreads();
    #pragma unroll
    for (int d = 1; d < 256; d <<= 1) {
        const int u = (t >= d) ? ss[t - d] : 0;
        __syncthreads();
        ss[t] += u;
        __syncthreads();
    }
    const int excl = ss[t] - v + partial[b];
    if (i < N_NODES) { off[i] = excl; cursor[i] = excl; }
    if (b == 0 && t == 0) off[N_NODES] = E_EDGES;
}

__global__ __launch_bounds__(256) void k_fill(
    const int* __restrict__ ei, const float* __restrict__ ea,
    int* __restrict__ cursor, int2* __restrict__ csr)
{
    const int e = blockIdx.x * 256 + threadIdx.x;
    if (e >= E_EDGES) return;
    const int dst = ei[E_EDGES + e];
    const int pos = atomicAdd(&cursor[dst], 1);
    csr[pos] = make_int2(ei[e], __float_as_int(ea[e]));
}

// ---------------------------------------------------------------------------
// k_layer: NPB=16 split-bf16 MFMA node update. R11 change: the serial gather
// remainder (up to 7 dependent csr->h->VALU rounds per node) is replaced by
// ONE masked batch of 8: indices clamped to hi-1 (segment non-empty under
// the uniform branch), all loads issued in parallel, contributions gated by
// valid ? term : 0.f. Accumulation order matches the old loop exactly and
// +0.f on a non-negative accumulator is exact -> bit-identical results.
// ---------------------------------------------------------------------------
#define NPB 16
__global__ __launch_bounds__(256) void k_layer(
    const int* __restrict__ off, const int2* __restrict__ csr,
    const u16* __restrict__ h_in, u16* __restrict__ h_out,
    const float* __restrict__ ew, const float* __restrict__ eb,
    const float* __restrict__ eps_p,
    const u16* __restrict__ wh1, const u16* __restrict__ wl1,
    const float* __restrict__ b1, const float* __restrict__ bn_g,
    const float* __restrict__ bn_b, const float* __restrict__ bn_m,
    const float* __restrict__ bn_v,
    const u16* __restrict__ wh2, const u16* __restrict__ wl2,
    const float* __restrict__ b2,
    const int first_layer, const int last_layer,
    const float* __restrict__ aw, const float* __restrict__ ab,
    float* __restrict__ out)
{
    const int n0 = blockIdx.x * NPB;
    const int t  = threadIdx.x;

    __shared__ __align__(16) u16   s_pool[2 * 16 * 136];
    __shared__ __align__(16) u16   s_th[16 * 136];
    __shared__ __align__(16) u16   s_tl[16 * 136];
    __shared__ __align__(16) float s_r [16 * 128];
    u16* s_zh = s_pool;
    u16* s_zl = s_pool + 16 * 136;
    float* s_hd = (float*)s_pool;

    const float ep1 = 1.f + eps_p[0];

    // ---- phase 1: gather. quarter-wave (16 lanes) owns one node ----
    {
        const int q = t >> 4;            // node slot 0..15
        const int c = (t & 15) * 8;      // channel base (8 ch/lane)
        const int n = n0 + q;

        const float4 wv0 = *(const float4*)&ew[c];
        const float4 wv1 = *(const float4*)&ew[c + 4];
        const float4 bv0 = *(const float4*)&eb[c];
        const float4 bv1 = *(const float4*)&eb[c + 4];

        int i        = off[n];
        const int hi = off[n + 1];

        float a0[8], a1[8];
        #pragma unroll
        for (int j = 0; j < 8; ++j) { a0[j] = 0.f; a1[j] = 0.f; }

        int2 p[8];
        bool have = (i + 7 < hi);
        if (have) {
            #pragma unroll
            for (int u = 0; u < 8; ++u) p[u] = csr[i + u];
        }
        while (have) {
            uint4 hq[8];
            #pragma unroll
            for (int u = 0; u < 8; ++u)
                hq[u] = *(const uint4*)&h_in[(size_t)p[u].x * H + c];

            const int inext = i + 8;
            const bool more = (inext + 7 < hi);

            #pragma unroll
            for (int u = 0; u < 8; ++u) {
                const float a = __int_as_float(p[u].y);
                const float h0 = bf_lo(hq[u].x), h1 = bf_hi(hq[u].x);
                const float h2 = bf_lo(hq[u].y), h3 = bf_hi(hq[u].y);
                const float h4 = bf_lo(hq[u].z), h5 = bf_hi(hq[u].z);
                const float h6 = bf_lo(hq[u].w), h7 = bf_hi(hq[u].w);
                float* acc = (u & 1) ? a1 : a0;
                acc[0] += fmaxf(fmaf(a, wv0.x, h0) + bv0.x, 0.f);
                acc[1] += fmaxf(fmaf(a, wv0.y, h1) + bv0.y, 0.f);
                acc[2] += fmaxf(fmaf(a, wv0.z, h2) + bv0.z, 0.f);
                acc[3] += fmaxf(fmaf(a, wv0.w, h3) + bv0.w, 0.f);
                acc[4] += fmaxf(fmaf(a, wv1.x, h4) + bv1.x, 0.f);
                acc[5] += fmaxf(fmaf(a, wv1.y, h5) + bv1.y, 0.f);
                acc[6] += fmaxf(fmaf(a, wv1.z, h6) + bv1.z, 0.f);
                acc[7] += fmaxf(fmaf(a, wv1.w, h7) + bv1.w, 0.f);
            }
            if (more) {
                #pragma unroll
                for (int u = 0; u < 8; ++u) p[u] = csr[inext + u];
            }
            i = inext;
            have = more;
        }
        // tail: one masked batch of 8 (replaces up to 7 serial rounds)
        if (i < hi) {
            int2 pt[8];
            #pragma unroll
            for (int u = 0; u < 8; ++u) {
                const int idx = (i + u < hi) ? (i + u) : (hi - 1);
                pt[u] = csr[idx];
            }
            uint4 hq[8];
            #pragma unroll
            for (int u = 0; u < 8; ++u)
                hq[u] = *(const uint4*)&h_in[(size_t)pt[u].x * H + c];
            #pragma unroll
            for (int u = 0; u < 8; ++u) {
                const bool valid = (i + u < hi);
                const float a = __int_as_float(pt[u].y);
                const float h0 = bf_lo(hq[u].x), h1 = bf_hi(hq[u].x);
                const float h2 = bf_lo(hq[u].y), h3 = bf_hi(hq[u].y);
                const float h4 = bf_lo(hq[u].z), h5 = bf_hi(hq[u].z);
                const float h6 = bf_lo(hq[u].w), h7 = bf_hi(hq[u].w);
                a0[0] += valid ? fmaxf(fmaf(a, wv0.x, h0) + bv0.x, 0.f) : 0.f;
                a0[1] += valid ? fmaxf(fmaf(a, wv0.y, h1) + bv0.y, 0.f) : 0.f;
                a0[2] += valid ? fmaxf(fmaf(a, wv0.z, h2) + bv0.z, 0.f) : 0.f;
                a0[3] += valid ? fmaxf(fmaf(a, wv0.w, h3) + bv0.w, 0.f) : 0.f;
                a0[4] += valid ? fmaxf(fmaf(a, wv1.x, h4) + bv1.x, 0.f) : 0.f;
                a0[5] += valid ? fmaxf(fmaf(a, wv1.y, h5) + bv1.y, 0.f) : 0.f;
                a0[6] += valid ? fmaxf(fmaf(a, wv1.z, h6) + bv1.z, 0.f) : 0.f;
                a0[7] += valid ? fmaxf(fmaf(a, wv1.w, h7) + bv1.w, 0.f) : 0.f;
            }
        }
        #pragma unroll
        for (int j = 0; j < 8; ++j) a0[j] += a1[j];

        const uint4 ho = *(const uint4*)&h_in[(size_t)n * H + c];
        const float r0 = bf_lo(ho.x), r1 = bf_hi(ho.x);
        const float r2 = bf_lo(ho.y), r3 = bf_hi(ho.y);
        const float r4 = bf_lo(ho.z), r5 = bf_hi(ho.z);
        const float r6 = bf_lo(ho.w), r7 = bf_hi(ho.w);
        *(float4*)&s_r[q * 128 + c]     = make_float4(r0, r1, r2, r3);
        *(float4*)&s_r[q * 128 + c + 4] = make_float4(r4, r5, r6, r7);

        const float rr[8] = {r0, r1, r2, r3, r4, r5, r6, r7};
        #pragma unroll
        for (int k = 0; k < 4; ++k) {
            const float za = fmaf(ep1, rr[2*k],   a0[2*k]);
            const float zb = fmaf(ep1, rr[2*k+1], a0[2*k+1]);
            const u16 zha = f2bf(za), zhb = f2bf(zb);
            *(u32*)&s_zh[q * 136 + c + 2*k] = (u32)zha | ((u32)zhb << 16);
            *(u32*)&s_zl[q * 136 + c + 2*k] =
                pack2bf(za - bfu(zha), zb - bfu(zhb));
        }
    }
    __syncthreads();

    const int lane = t & 63;
    const int wv   = t >> 6;
    const int l15  = lane & 15;
    const int kl   = lane >> 4;
    const int nt0  = wv * 2, nt1 = wv * 2 + 1;
    const int nA   = nt0 * 16 + l15;
    const int nB   = nt1 * 16 + l15;

    // ---- phase 2: t = relu(BN(z @ w1 + b1))  [MFMA, 16 real rows] ----
    {
        f32x4 acc0 = {0.f, 0.f, 0.f, 0.f};
        f32x4 acc1 = {0.f, 0.f, 0.f, 0.f};
        #pragma unroll
        for (int ks = 0; ks < 4; ++ks) {
            const int aoff = l15 * 136 + ks * 32 + kl * 8;
            const bf16x8 ah = *(const bf16x8*)&s_zh[aoff];
            const bf16x8 al = *(const bf16x8*)&s_zl[aoff];
            const int bo0 = (ks * 8 + nt0) * 512 + lane * 8;
            const int bo1 = (ks * 8 + nt1) * 512 + lane * 8;
            const bf16x8 bh0 = *(const bf16x8*)&wh1[bo0];
            const bf16x8 bl0 = *(const bf16x8*)&wl1[bo0];
            const bf16x8 bh1 = *(const bf16x8*)&wh1[bo1];
            const bf16x8 bl1 = *(const bf16x8*)&wl1[bo1];
            acc0 = MFMA16(ah, bh0, acc0);
            acc0 = MFMA16(al, bh0, acc0);
            acc0 = MFMA16(ah, bl0, acc0);
            acc1 = MFMA16(ah, bh1, acc1);
            acc1 = MFMA16(al, bh1, acc1);
            acc1 = MFMA16(ah, bl1, acc1);
        }
        const float sc0 = bn_g[nA] * rsqrtf(bn_v[nA] + BN_EPS);
        const float sh0 = fmaf(b1[nA] - bn_m[nA], sc0, bn_b[nA]);
        const float sc1 = bn_g[nB] * rsqrtf(bn_v[nB] + BN_EPS);
        const float sh1 = fmaf(b1[nB] - bn_m[nB], sc1, bn_b[nB]);

        #pragma unroll
        for (int r = 0; r < 4; ++r) {
            const int m = kl * 4 + r;
            const float t0 = fmaxf(fmaf(acc0[r], sc0, sh0), 0.f);
            const float t1 = fmaxf(fmaf(acc1[r], sc1, sh1), 0.f);
            const u16 th0 = f2bf(t0), th1 = f2bf(t1);
            s_th[m * 136 + nA] = th0;
            s_tl[m * 136 + nA] = f2bf(t0 - bfu(th0));
            s_th[m * 136 + nB] = th1;
            s_tl[m * 136 + nB] = f2bf(t1 - bfu(th1));
        }
    }
    __syncthreads();

    // ---- phase 3: c = t @ w2 + b2; h' = relu(c) (+res); store / head ----
    {
        f32x4 acc0 = {0.f, 0.f, 0.f, 0.f};
        f32x4 acc1 = {0.f, 0.f, 0.f, 0.f};
        #pragma unroll
        for (int ks = 0; ks < 4; ++ks) {
            const int aoff = l15 * 136 + ks * 32 + kl * 8;
            const bf16x8 ah = *(const bf16x8*)&s_th[aoff];
            const bf16x8 al = *(const bf16x8*)&s_tl[aoff];
            const int bo0 = (ks * 8 + nt0) * 512 + lane * 8;
            const int bo1 = (ks * 8 + nt1) * 512 + lane * 8;
            const bf16x8 bh0 = *(const bf16x8*)&wh2[bo0];
            const bf16x8 bl0 = *(const bf16x8*)&wl2[bo0];
            const bf16x8 bh1 = *(const bf16x8*)&wh2[bo1];
            const bf16x8 bl1 = *(const bf16x8*)&wl2[bo1];
            acc0 = MFMA16(ah, bh0, acc0);
            acc0 = MFMA16(al, bh0, acc0);
            acc0 = MFMA16(ah, bl0, acc0);
            acc1 = MFMA16(ah, bh1, acc1);
            acc1 = MFMA16(al, bh1, acc1);
            acc1 = MFMA16(ah, bl1, acc1);
        }
        const float bb0 = b2[nA];
        const float bb1 = b2[nB];

        float hv0[4], hv1[4];
        #pragma unroll
        for (int r = 0; r < 4; ++r) {
            const int m = kl * 4 + r;
            hv0[r] = fmaxf(acc0[r] + bb0, 0.f);
            hv1[r] = fmaxf(acc1[r] + bb1, 0.f);
            if (!first_layer) {
                hv0[r] += s_r[m * 128 + nA];
                hv1[r] += s_r[m * 128 + nB];
            }
        }

        if (!last_layer) {
            // coalesced store: pack bf16 into reused s_th, then 16B/thread
            __syncthreads();                     // all s_th/s_tl reads done
            u16* s_ho = s_th;                    // 16 x 128 u16 = 4 KB
            #pragma unroll
            for (int r = 0; r < 4; ++r) {
                const int m = kl * 4 + r;
                s_ho[m * 128 + nA] = f2bf(hv0[r]);
                s_ho[m * 128 + nB] = f2bf(hv1[r]);
            }
            __syncthreads();
            const size_t base = (size_t)n0 * H;  // u16 elements
            *(uint4*)&h_out[base + t * 8] = *(const uint4*)&s_ho[t * 8];
        } else {
            #pragma unroll
            for (int r = 0; r < 4; ++r) {
                const int m = kl * 4 + r;
                s_hd[m * 128 + nA] = hv0[r];
                s_hd[m * 128 + nB] = hv1[r];
            }
        }
    }

    if (last_layer) {
        __syncthreads();
        const int q = t >> 4;
        const int c = (t & 15) * 8;
        float mu = 0.f, sg = 0.f;
        #pragma unroll
        for (int j = 0; j < 8; ++j) {
            const float hv = s_hd[q * 128 + c + j];
            const float2 awj = *(const float2*)&aw[(c + j) * 2];
            mu = fmaf(hv, awj.x, mu);
            sg = fmaf(hv, awj.y, sg);
        }
        #pragma unroll
        for (int s = 1; s < 16; s <<= 1) {
            mu += __shfl_xor(mu, s);
            sg += __shfl_xor(sg, s);
        }
        if ((t & 15) == 0) {
            const float o1 = sg + ab[1];
            const float sp = (o1 > 0.f) ? (o1 + log1pf(expf(-o1)))
                                        : log1pf(expf(o1));
            out[(size_t)(n0 + q) * 2 + 0] = mu + ab[0];
            out[(size_t)(n0 + q) * 2 + 1] = sp;
        }
    }
}

// ---------------------------------------------------------------------------
extern "C" void kernel_launch(void* const* d_in, const int* in_sizes, int n_in,
                              void* d_out, int out_size, void* d_ws, size_t ws_size,
                              hipStream_t stream)
{
    const float* ensemble = (const float*)d_in[0];
    const float* x        = (const float*)d_in[1];
    const int*   ei       = (const int*)d_in[2];
    const float* ea       = (const float*)d_in[3];
    const float* phi_w1   = (const float*)d_in[4];
    const float* phi_b1   = (const float*)d_in[5];
    const float* phi_w2   = (const float*)d_in[6];
    const float* phi_b2   = (const float*)d_in[7];
    const float* rho_w1   = (const float*)d_in[8];
    const float* rho_b1   = (const float*)d_in[9];
    const float* rho_w2   = (const float*)d_in[10];
    const float* rho_b2   = (const float*)d_in[11];
    const float* dr_w     = (const float*)d_in[12];
    const float* dr_b     = (const float*)d_in[13];
    const float* conv_eps = (const float*)d_in[14];
    const float* edge_w   = (const float*)d_in[15];
    const float* edge_b   = (const float*)d_in[16];
    const float* mlp_w1   = (const float*)d_in[17];
    const float* mlp_b1   = (const float*)d_in[18];
    const float* bn_g     = (const float*)d_in[19];
    const float* bn_b     = (const float*)d_in[20];
    const float* bn_m     = (const float*)d_in[21];
    const float* bn_v     = (const float*)d_in[22];
    const float* mlp_w2   = (const float*)d_in[23];
    const float* mlp_b2   = (const float*)d_in[24];
    const float* aggr_w   = (const float*)d_in[25];
    const float* aggr_b   = (const float*)d_in[26];

    float* out = (float*)d_out;

    // workspace layout — R2 footprint + 1 KB scan partials.
    float* Wf1     = (float*)d_ws;                          // H*H
    float* bf1     = Wf1 + H * H;                           // H
    float* Wf2     = bf1 + H;                               // H*H
    float* bf2     = Wf2 + H * H;                           // H
    int*   off     = (int*)(bf2 + H);                       // N+2 (padded)
    int*   cursor  = off + (N_NODES + 2);                   // N
    int2*  csr     = (int2*)(cursor + N_NODES);             // E (8B aligned)
    u16*   h_a     = (u16*)(csr + E_EDGES);                 // N*H bf16
    u16*   h_b     = h_a + (size_t)N_NODES * H;             // N*H bf16
    u16*   wpk     = h_b + (size_t)N_NODES * H;             // 196608 u16
    u16*   wpk2    = wpk + 196608;                          // 81920 u16
    int*   partial = (int*)(wpk2 + 81920);                  // SCAN_NB ints

    // phi-sum planes ALIAS the h buffers (dead at that point in the stream)
    u16*   hh      = h_b;
    u16*   hl      = h_a;

    const int eblocks = (E_EDGES + 255) / 256;

    // fold weights, pack MFMA weights
    k_fold<<<256, 256, 0, stream>>>(phi_w2, phi_b2, rho_w1, rho_b1,
                                    rho_w2, rho_b2, dr_w, dr_b,
                                    Wf1, bf1, Wf2, bf2);
    k_pack<<<384, 256, 0, stream>>>(mlp_w1, mlp_w2, wpk);
    k_pack2<<<160, 256, 0, stream>>>(phi_w1, Wf1, Wf2, dr_w, wpk2);

    // embed: streaming phi-sum, then matmul chain -> h_a
    k_phi<<<N_NODES / 16, 256, 0, stream>>>(ensemble, phi_b1, wpk2, hh, hl);
    k_emb2<<<N_NODES / 16, 256, 0, stream>>>(x, hh, hl, bf1, bf2, wpk2, h_a);

    // CSR build (once) — multi-block scan
    hipMemsetAsync(off, 0, (N_NODES + 1) * sizeof(int), stream);
    k_count<<<eblocks, 256, 0, stream>>>(ei, off);
    k_scanA<<<SCAN_NB, 256, 0, stream>>>(off, partial);
    k_scanB<<<1, 256, 0, stream>>>(partial);
    k_scanC<<<SCAN_NB, 256, 0, stream>>>(partial, off, cursor);
    k_fill<<<eblocks, 256, 0, stream>>>(ei, ea, cursor, csr);

    // fused GINE layers (double-buffered h; last layer writes head to out)
    u16* hin = h_a; u16* hout = h_b;
    for (int i = 0; i < L_LAYERS; ++i) {
        const u16* wh1 = wpk + ((size_t)i * 2 + 0) * 32768;
        const u16* wl1 = wh1 + 16384;
        const u16* wh2 = wpk + ((size_t)i * 2 + 1) * 32768;
        const u16* wl2 = wh2 + 16384;
        k_layer<<<N_NODES / NPB, 256, 0, stream>>>(
            off, csr, hin, hout,
            edge_w + (size_t)i * H, edge_b + (size_t)i * H, conv_eps + i,
            wh1, wl1,
            mlp_b1 + (size_t)i * H,
            bn_g + (size_t)i * H, bn_b + (size_t)i * H,
            bn_m + (size_t)i * H, bn_v + (size_t)i * H,
            wh2, wl2, mlp_b2 + (size_t)i * H,
            (i == 0) ? 1 : 0, (i == L_LAYERS - 1) ? 1 : 0,
            aggr_w, aggr_b, out);
        u16* tmp = hin; hin = hout; hout = tmp;
    }
}